// Round 5
// baseline (975.537 us; speedup 1.0000x reference)
//
#include <hip/hip_runtime.h>
#include <hip/hip_bf16.h>

// Fused 5-layer MLP 203->175->150->128->80->48, tanh on 1-4, B=131072, fp32 I/O.
// R5: SINGLE ordinary kernel. Phase 1: every block redundantly splits ALL
// weights (hi/lo bf16, B-fragment order) into d_ws — identical bytes from all
// blocks, so write races are benign and each block reads only its own writes
// (no inter-block sync, no dispatch-order assumption). Phase 2: R4 main loop —
// L1: x hi/lo split (3 MFMAs/chunk); L2-5: plain-bf16 acts in LDS (1 b128
// A-read), weight hi+lo planes (2 MFMAs/chunk). B-frags direct from global
// (L2-resident). Packed v_cvt_pk_bf16_f32 for all fp32->bf16 pair splits.

typedef short short8 __attribute__((ext_vector_type(8)));
typedef float f32x16 __attribute__((ext_vector_type(16)));
typedef unsigned int uint;
typedef unsigned short ushort;

#define SROWU 184   // act plane stride in ushorts (368 B rows, 16B-aligned)
#define XSTR 20     // xst stride (dwords)
#define GRID 1024

union BF2U { __hip_bfloat162 b; uint u; };

__device__ __forceinline__ uint pk_bf16(float a, float b) {   // a->low16, b->high16
    BF2U t; t.b = __float22bfloat162_rn(make_float2(a, b)); return t.u;
}
__device__ __forceinline__ ushort f2bf(float f) {
    uint u = __float_as_uint(f);
    u += 0x7FFFu + ((u >> 16) & 1u);
    return (ushort)(u >> 16);
}
__device__ __forceinline__ float fast_tanh(float x) {
    float e = __expf(2.0f * x);
    return 1.0f - 2.0f / (e + 1.0f);
}

union U4S8 { uint4 u; short8 s; };

// ---------------- prep: split one tile-pair (b, lane l) into ws --------------
// pair p = c*NT + t: 2048 B = [hi 1024][lo 1024]; lane l: B[k=(l>>5)*8+j][n=l&31]
__device__ __forceinline__ void prep_pair(int b, int l,
    const float* __restrict__ W1, const float* __restrict__ W2,
    const float* __restrict__ W3, const float* __restrict__ W4,
    const float* __restrict__ W5, char* __restrict__ ws)
{
    int layer, local;
    if      (b <  78) { layer = 0; local = b; }
    else if (b < 133) { layer = 1; local = b - 78; }
    else if (b < 173) { layer = 2; local = b - 133; }
    else if (b < 197) { layer = 3; local = b - 173; }
    else              { layer = 4; local = b - 197; }
    const int NTa[5]  = {6, 5, 4, 3, 2};
    const int FINa[5] = {203, 175, 150, 128, 80};
    const int FOa[5]  = {175, 150, 128, 80, 48};
    const float* Wp = (layer == 0) ? W1 : (layer == 1) ? W2 : (layer == 2) ? W3
                    : (layer == 3) ? W4 : W5;
    const int nt = NTa[layer], fin = FINa[layer], fout = FOa[layer];
    const int c = local / nt, t = local % nt;
    const int n  = t * 32 + (l & 31);
    const int kb = c * 16 + (l >> 5) * 8;
    float v[8];
#pragma unroll
    for (int j = 0; j < 8; ++j) {
        int k = kb + j;
        v[j] = (n < fout && k < fin) ? Wp[(size_t)n * fin + k] : 0.0f;
    }
    uint hw[4], lw[4];
#pragma unroll
    for (int j = 0; j < 4; ++j) {
        uint hp = pk_bf16(v[2*j], v[2*j+1]);
        float h0 = __uint_as_float(hp << 16);
        float h1 = __uint_as_float(hp & 0xFFFF0000u);
        hw[j] = hp;
        lw[j] = pk_bf16(v[2*j] - h0, v[2*j+1] - h1);
    }
    uint4* dst = (uint4*)(ws + (size_t)b * 2048) + l;
    dst[0]  = make_uint4(hw[0], hw[1], hw[2], hw[3]);   // hi plane
    dst[64] = make_uint4(lw[0], lw[1], lw[2], lw[3]);   // lo plane (+1024 B)
}

// ---------------- D-phase: acc -> tanh -> plain bf16 actP (or global out) ----
template<int MT, int NT, int FOUT, int PADN, bool ACT, bool LAST>
__device__ __forceinline__ void d_phase(f32x16* acc, ushort* oP, float* outg,
                                        int row0, int rg, int ns, int lx, int lh, int tid)
{
#pragma unroll
    for (int m = 0; m < MT; ++m) {
        int t = ns + 2 * m;
        if (t < NT) {
#pragma unroll
            for (int r = 0; r < 16; ++r) {
                float vv = acc[m][r];
                if (ACT) vv = fast_tanh(vv);
                int rowl = rg * 32 + (r & 3) + 8 * (r >> 2) + 4 * lh;
                int col  = t * 32 + lx;
                if (LAST) {
                    if (col < 48) outg[(size_t)(row0 + rowl) * 48 + col] = vv;
                } else if (col < FOUT) {
                    oP[rowl * SROWU + col] = f2bf(vv);
                }
            }
        }
    }
    if (!LAST) {
        if (PADN > 0) {
            for (int idx = tid; idx < 64 * PADN; idx += 256) {
                int row = idx / PADN, p = idx % PADN;
                oP[row * SROWU + FOUT + p] = 0;
            }
        }
        __syncthreads();    // outputs visible to next layer
    }
}

// ---------------- layers 2-5: plain-bf16 A from LDS, B direct from global ----
template<int KC, int NT, int FOUT, int PADN, bool ACT, bool LAST>
__device__ __forceinline__ void run_layer(const char* __restrict__ wsL,
    const float* __restrict__ bias, const ushort* aP, ushort* oP, float* outg,
    int row0, int l, int rg, int ns, int lx, int lh, int tid)
{
    constexpr int MT = (NT + 1) / 2;
    f32x16 acc[MT];
#pragma unroll
    for (int m = 0; m < MT; ++m) {
        int t = ns + 2 * m;
        float bv = 0.0f;
        if (t < NT) { int n = t * 32 + lx; bv = (n < FOUT) ? bias[n] : 0.0f; }
#pragma unroll
        for (int r = 0; r < 16; ++r) acc[m][r] = bv;
    }

#pragma unroll
    for (int c = 0; c < KC; ++c) {
        U4S8 bh[MT], bl[MT];
#pragma unroll
        for (int m = 0; m < MT; ++m) {
            int t = ns + 2 * m;
            if (t < NT) {
                const uint4* w = (const uint4*)wsL + (size_t)((c * NT + t) * 2) * 64 + l;
                bh[m].u = w[0];      // hi plane
                bl[m].u = w[64];     // lo plane
            }
        }
        U4S8 a;
        a.u = *(const uint4*)(aP + (rg * 32 + lx) * SROWU + c * 16 + lh * 8);  // b128
#pragma unroll
        for (int m = 0; m < MT; ++m) {
            int t = ns + 2 * m;
            if (t < NT) {
                acc[m] = __builtin_amdgcn_mfma_f32_32x32x16_bf16(a.s, bh[m].s, acc[m], 0, 0, 0);
                acc[m] = __builtin_amdgcn_mfma_f32_32x32x16_bf16(a.s, bl[m].s, acc[m], 0, 0, 0);
            }
        }
    }
    if (!LAST) __syncthreads();   // all actP reads done before overwrite
    d_phase<MT, NT, FOUT, PADN, ACT, LAST>(acc, oP, outg, row0, rg, ns, lx, lh, tid);
}

// ---------------- layer 1: x via xst LDS buffer, hi/lo split, 3 MFMAs --------
__device__ __forceinline__ void run_first(const float* __restrict__ x,
    const char* __restrict__ wsL, const float* __restrict__ bias,
    ushort* oP, float* xst, int row0, int l, int rg, int ns, int lx, int lh, int tid)
{
    constexpr int KC = 13, MT = 3;
    f32x16 acc[MT];
#pragma unroll
    for (int m = 0; m < MT; ++m) {
        int n = (ns + 2 * m) * 32 + lx;
        float bv = (n < 175) ? bias[n] : 0.0f;
#pragma unroll
        for (int r = 0; r < 16; ++r) acc[m][r] = bv;
    }

#pragma unroll
    for (int i = 0; i < 4; ++i) {        // stage chunk 0 (coalesced)
        int e = i * 256 + tid, row = e >> 4, kk = e & 15;
        xst[row * XSTR + kk] = x[(size_t)(row0 + row) * 203 + kk];
    }
    __syncthreads();

#pragma unroll
    for (int c = 0; c < KC; ++c) {
        U4S8 bh[MT], bl[MT];
#pragma unroll
        for (int m = 0; m < MT; ++m) {
            const uint4* w = (const uint4*)wsL + (size_t)((c * 6 + ns + 2 * m) * 2) * 64 + l;
            bh[m].u = w[0];
            bl[m].u = w[64];
        }
        float pre[4];
        if (c < 12) {   // register-prefetch next chunk (coalesced)
#pragma unroll
            for (int i = 0; i < 4; ++i) {
                int e = i * 256 + tid, row = e >> 4, kk = e & 15, k = (c + 1) * 16 + kk;
                pre[i] = (k < 203) ? x[(size_t)(row0 + row) * 203 + k] : 0.0f;
            }
        }
        const float* apf = xst + (rg * 32 + lx) * XSTR + lh * 8;
        float4 v0 = *(const float4*)apf;
        float4 v1 = *(const float4*)(apf + 4);
        float vv[8] = {v0.x, v0.y, v0.z, v0.w, v1.x, v1.y, v1.z, v1.w};
        U4S8 ah, al;
        uint* aHu = (uint*)&ah; uint* aLu = (uint*)&al;
#pragma unroll
        for (int j = 0; j < 4; ++j) {
            uint hp = pk_bf16(vv[2*j], vv[2*j+1]);
            float h0 = __uint_as_float(hp << 16);
            float h1 = __uint_as_float(hp & 0xFFFF0000u);
            aHu[j] = hp;
            aLu[j] = pk_bf16(vv[2*j] - h0, vv[2*j+1] - h1);
        }
#pragma unroll
        for (int m = 0; m < MT; ++m) {
            acc[m] = __builtin_amdgcn_mfma_f32_32x32x16_bf16(ah.s, bh[m].s, acc[m], 0, 0, 0);
            acc[m] = __builtin_amdgcn_mfma_f32_32x32x16_bf16(al.s, bh[m].s, acc[m], 0, 0, 0);
            acc[m] = __builtin_amdgcn_mfma_f32_32x32x16_bf16(ah.s, bl[m].s, acc[m], 0, 0, 0);
        }
        if (c < 12) {
            __syncthreads();
#pragma unroll
            for (int i = 0; i < 4; ++i) {
                int e = i * 256 + tid, row = e >> 4, kk = e & 15;
                xst[row * XSTR + kk] = pre[i];
            }
            __syncthreads();
        }
    }
    d_phase<MT, 6, 175, 1, true, false>(acc, oP, nullptr, row0, rg, ns, lx, lh, tid);
}

__global__ __launch_bounds__(256, 4)
void mlp_fused(const float* __restrict__ x,
               const float* __restrict__ W1, const float* __restrict__ b1,
               const float* __restrict__ W2, const float* __restrict__ b2,
               const float* __restrict__ W3, const float* __restrict__ b3,
               const float* __restrict__ W4, const float* __restrict__ b4,
               const float* __restrict__ W5, const float* __restrict__ b5,
               char* __restrict__ ws, float* __restrict__ out)
{
    __shared__ __align__(16) ushort actP[64 * SROWU];  // 23552 B
    __shared__ __align__(16) float  xst[64 * XSTR];    //  5120 B -> 28672 B total

    const int tid = threadIdx.x;

    // ---- phase 1: this block redundantly splits ALL weights into ws ----
    // (identical bytes from every block -> benign races; we read only what
    //  our own threads wrote -> no inter-block ordering assumption)
#pragma unroll 1
    for (int task = tid; task < 207 * 64; task += 256)
        prep_pair(task >> 6, task & 63, W1, W2, W3, W4, W5, ws);
    __threadfence();     // drain writes / invalidate L1 so reads see them
    __syncthreads();

    const int l = tid & 63, w = tid >> 6;
    const int rg = w >> 1, ns = w & 1;
    const int lx = l & 31, lh = l >> 5;

#pragma unroll 1
    for (int it = 0; it < 2; ++it) {
        const int row0 = (blockIdx.x + it * GRID) * 64;
        run_first(x, ws, b1, actP, xst, row0, l, rg, ns, lx, lh, tid);
        run_layer<11, 5, 150, 10, true,  false>(ws +  78 * 2048, b2, actP, actP, nullptr, row0, l, rg, ns, lx, lh, tid);
        run_layer<10, 4, 128,  0, true,  false>(ws + 133 * 2048, b3, actP, actP, nullptr, row0, l, rg, ns, lx, lh, tid);
        run_layer< 8, 3,  80,  0, true,  false>(ws + 173 * 2048, b4, actP, actP, nullptr, row0, l, rg, ns, lx, lh, tid);
        run_layer< 5, 2,  48,  0, false, true >(ws + 197 * 2048, b5, actP, actP, out,     row0, l, rg, ns, lx, lh, tid);
    }
}

extern "C" void kernel_launch(void* const* d_in, const int* in_sizes, int n_in,
                              void* d_out, int out_size, void* d_ws, size_t ws_size,
                              hipStream_t stream) {
    (void)in_sizes; (void)n_in; (void)ws_size; (void)out_size;
    const float* x  = (const float*)d_in[0];
    const float* W1 = (const float*)d_in[1];
    const float* b1 = (const float*)d_in[2];
    const float* W2 = (const float*)d_in[3];
    const float* b2 = (const float*)d_in[4];
    const float* W3 = (const float*)d_in[5];
    const float* b3 = (const float*)d_in[6];
    const float* W4 = (const float*)d_in[7];
    const float* b4 = (const float*)d_in[8];
    const float* W5 = (const float*)d_in[9];
    const float* b5 = (const float*)d_in[10];
    float* out = (float*)d_out;
    char* ws = (char*)d_ws;      // needs 423936 B

    hipLaunchKernelGGL(mlp_fused, dim3(GRID), dim3(256), 0, stream,
                       x, W1, b1, W2, b2, W3, b3, W4, b4, W5, b5, ws, out);
}

// Round 6
// 437.799 us; speedup vs baseline: 2.2283x; 2.2283x over previous
//
#include <hip/hip_runtime.h>
#include <hip/hip_bf16.h>

// Fused 5-layer MLP 203->175->150->128->80->48, tanh on 1-4, B=131072, fp32 I/O.
// R6: single kernel, NO d_ws. Per layer, each block splits the fp32 weights
// (L2-resident) into hi/lo-bf16 B-fragments directly in LDS, double-buffered
// per 16-wide k-chunk (register prefetch of chunk c+1 overlaps MFMAs on c;
// one LDS-only barrier per chunk). L1: x hi/lo split, 3 MFMAs/chunk (xst LDS
// staging, single-buffered). L2-5: plain-bf16 acts in LDS (verified R5:
// absmax 1.95e-3), weight hi+lo planes, 2 MFMAs/chunk. 32x32x16 bf16 MFMA,
// block = 64 rows, 4 waves = 2 row-groups x 2 n-split. LDS 49 KB -> 3 blk/CU.

typedef short short8 __attribute__((ext_vector_type(8)));
typedef float f32x16 __attribute__((ext_vector_type(16)));
typedef unsigned int uint;
typedef unsigned short ushort;

#define SROWU 184   // act plane stride in ushorts (368 B rows, 16B-aligned)
#define XSTR 20     // xst stride (dwords): 4-dword aligned, period-8 banks
#define GRID 2048

union BF2U { __hip_bfloat162 b; uint u; };

__device__ __forceinline__ uint pk_bf16(float a, float b) {   // a->low16, b->high16
    BF2U t; t.b = __float22bfloat162_rn(make_float2(a, b)); return t.u;
}
__device__ __forceinline__ ushort f2bf(float f) {
    uint u = __float_as_uint(f);
    u += 0x7FFFu + ((u >> 16) & 1u);
    return (ushort)(u >> 16);
}
__device__ __forceinline__ float fast_tanh(float x) {
    float e = __expf(2.0f * x);
    return 1.0f - 2.0f / (e + 1.0f);
}

union U4S8 { uint4 u; short8 s; };

// ---- weight chunk build: load fp32 W values for chunk c into registers ------
// task idx -> (t = idx>>6, l = idx&63); lane l of tile t holds
// B[k = c*16 + (l>>5)*8 + j][n = t*32 + (l&31)] = W[n][k], zero-padded.
template<int NT, int FIN, int FOUT, int TPT>
__device__ __forceinline__ void load_w(const float* __restrict__ W, int c, int tid,
                                       float (&v)[TPT][8])
{
#pragma unroll
    for (int i = 0; i < TPT; ++i) {
        int idx = i * 256 + tid;
        if (idx < NT * 64) {
            int t = idx >> 6, l = idx & 63;
            int n  = t * 32 + (l & 31);
            int kb = c * 16 + (l >> 5) * 8;
            const float* wr = W + (size_t)n * FIN + kb;
            bool nok = (n < FOUT);
#pragma unroll
            for (int j = 0; j < 8; ++j)
                v[i][j] = (nok && (kb + j) < FIN) ? wr[j] : 0.0f;
        }
    }
}

// split registers -> hi/lo bf16 planes in LDS (dst = chunk half base)
template<int NT, int TPT>
__device__ __forceinline__ void store_w(char* __restrict__ dst, int tid,
                                        const float (&v)[TPT][8])
{
#pragma unroll
    for (int i = 0; i < TPT; ++i) {
        int idx = i * 256 + tid;
        if (idx < NT * 64) {
            int t = idx >> 6, l = idx & 63;
            uint hw[4], lw[4];
#pragma unroll
            for (int j = 0; j < 4; ++j) {
                uint hp = pk_bf16(v[i][2*j], v[i][2*j+1]);
                float h0 = __uint_as_float(hp << 16);
                float h1 = __uint_as_float(hp & 0xFFFF0000u);
                hw[j] = hp;
                lw[j] = pk_bf16(v[i][2*j] - h0, v[i][2*j+1] - h1);
            }
            uint4* d = (uint4*)(dst + t * 2048) + l;
            d[0]  = make_uint4(hw[0], hw[1], hw[2], hw[3]);   // hi plane
            d[64] = make_uint4(lw[0], lw[1], lw[2], lw[3]);   // lo plane (+1024 B)
        }
    }
}

// ---------------- D-phase: acc -> tanh -> plain bf16 actP (or global out) ----
template<int MT, int NT, int FOUT, int PADN, bool ACT, bool LAST>
__device__ __forceinline__ void d_phase(f32x16* acc, ushort* oP, float* outg,
                                        int row0, int rg, int ns, int lx, int lh, int tid)
{
#pragma unroll
    for (int m = 0; m < MT; ++m) {
        int t = ns + 2 * m;
        if (t < NT) {
#pragma unroll
            for (int r = 0; r < 16; ++r) {
                float vv = acc[m][r];
                if (ACT) vv = fast_tanh(vv);
                int rowl = rg * 32 + (r & 3) + 8 * (r >> 2) + 4 * lh;
                int col  = t * 32 + lx;
                if (LAST) {
                    if (col < 48) outg[(size_t)(row0 + rowl) * 48 + col] = vv;
                } else if (col < FOUT) {
                    oP[rowl * SROWU + col] = f2bf(vv);
                }
            }
        }
    }
    if (!LAST) {
        if (PADN > 0) {
            for (int idx = tid; idx < 64 * PADN; idx += 256) {
                int row = idx / PADN, p = idx % PADN;
                oP[row * SROWU + FOUT + p] = 0;
            }
        }
        __syncthreads();    // post-D: outputs visible to next layer
    }
}

// ---------------- layers 2-5: A plain bf16 from actP, B built into wb --------
template<int KC, int NT, int FIN, int FOUT, int PADN, bool ACT, bool LAST>
__device__ __forceinline__ void run_layer(const float* __restrict__ W,
    const float* __restrict__ bias, const ushort* aP, ushort* oP, float* outg,
    char* wb, int row0, int l, int rg, int ns, int lx, int lh, int tid)
{
    constexpr int MT  = (NT + 1) / 2;
    constexpr int TPT = (NT * 64 + 255) / 256;
    constexpr int HB  = NT * 2048;            // half-buffer stride

    f32x16 acc[MT];
#pragma unroll
    for (int m = 0; m < MT; ++m) {
        int t = ns + 2 * m;
        float bv = 0.0f;
        if (t < NT) { int n = t * 32 + lx; bv = (n < FOUT) ? bias[n] : 0.0f; }
#pragma unroll
        for (int r = 0; r < 16; ++r) acc[m][r] = bv;
    }

    {   // build chunk 0 -> half 0 (prev layer's wb reads fenced by post-D barrier)
        float v0[TPT][8];
        load_w<NT, FIN, FOUT, TPT>(W, 0, tid, v0);
        store_w<NT, TPT>(wb, tid, v0);
    }
    __syncthreads();

#pragma unroll 1
    for (int c = 0; c < KC; ++c) {
        float pv[TPT][8];
        if (c + 1 < KC) load_w<NT, FIN, FOUT, TPT>(W, c + 1, tid, pv);

        const char* cb = wb + (c & 1) * HB;
        U4S8 bh[MT], bl[MT];
#pragma unroll
        for (int m = 0; m < MT; ++m) {
            int t = ns + 2 * m;
            if (t < NT) {
                const uint4* wp = (const uint4*)(cb + t * 2048) + l;
                bh[m].u = wp[0];
                bl[m].u = wp[64];
            }
        }
        U4S8 a;
        a.u = *(const uint4*)(aP + (rg * 32 + lx) * SROWU + c * 16 + lh * 8);
#pragma unroll
        for (int m = 0; m < MT; ++m) {
            int t = ns + 2 * m;
            if (t < NT) {
                acc[m] = __builtin_amdgcn_mfma_f32_32x32x16_bf16(a.s, bh[m].s, acc[m], 0, 0, 0);
                acc[m] = __builtin_amdgcn_mfma_f32_32x32x16_bf16(a.s, bl[m].s, acc[m], 0, 0, 0);
            }
        }
        if (c + 1 < KC) store_w<NT, TPT>(wb + ((c + 1) & 1) * HB, tid, pv);
        __syncthreads();   // chunk c+1 visible; also pre-D fence on last iter
    }
    d_phase<MT, NT, FOUT, PADN, ACT, LAST>(acc, oP, outg, row0, rg, ns, lx, lh, tid);
}

// ---------------- layer 1: x via xst (single-buffer), hi/lo split, 3 MFMAs ---
// wb aliases actP (uAbuf): weight reads all fenced before D-phase writes actP.
__device__ __forceinline__ void run_first(const float* __restrict__ x,
    const float* __restrict__ W1, const float* __restrict__ bias,
    ushort* oP, char* wb, float* xst,
    int row0, int l, int rg, int ns, int lx, int lh, int tid)
{
    constexpr int KC = 13, NT = 6, MT = 3, TPT = 2;
    constexpr int HB = NT * 2048;

    f32x16 acc[MT];
#pragma unroll
    for (int m = 0; m < MT; ++m) {
        int n = (ns + 2 * m) * 32 + lx;
        float bv = (n < 175) ? bias[n] : 0.0f;
#pragma unroll
        for (int r = 0; r < 16; ++r) acc[m][r] = bv;
    }

    {   // stage x chunk 0 (coalesced 16-dword runs) + build W1 chunk 0
        float v0[TPT][8];
        load_w<NT, 203, 175, TPT>(W1, 0, tid, v0);
#pragma unroll
        for (int i = 0; i < 4; ++i) {
            int e = i * 256 + tid, row = e >> 4, kk = e & 15;
            xst[row * XSTR + kk] = x[(size_t)(row0 + row) * 203 + kk];
        }
        store_w<NT, TPT>(wb, tid, v0);
    }
    __syncthreads();

#pragma unroll 1
    for (int c = 0; c < KC; ++c) {
        float pv[TPT][8], px[4];
        if (c + 1 < KC) {
            load_w<NT, 203, 175, TPT>(W1, c + 1, tid, pv);
#pragma unroll
            for (int i = 0; i < 4; ++i) {
                int e = i * 256 + tid, row = e >> 4, kk = e & 15, k = (c + 1) * 16 + kk;
                px[i] = (k < 203) ? x[(size_t)(row0 + row) * 203 + k] : 0.0f;
            }
        }
        const char* cb = wb + (c & 1) * HB;
        U4S8 bh[MT], bl[MT];
#pragma unroll
        for (int m = 0; m < MT; ++m) {
            const uint4* wp = (const uint4*)(cb + (ns + 2 * m) * 2048) + l;
            bh[m].u = wp[0];
            bl[m].u = wp[64];
        }
        const float* apf = xst + (rg * 32 + lx) * XSTR + lh * 8;
        float4 f0 = *(const float4*)apf;
        float4 f1 = *(const float4*)(apf + 4);
        float vv[8] = {f0.x, f0.y, f0.z, f0.w, f1.x, f1.y, f1.z, f1.w};
        U4S8 ah, al;
        uint* aHu = (uint*)&ah; uint* aLu = (uint*)&al;
#pragma unroll
        for (int j = 0; j < 4; ++j) {
            uint hp = pk_bf16(vv[2*j], vv[2*j+1]);
            float h0 = __uint_as_float(hp << 16);
            float h1 = __uint_as_float(hp & 0xFFFF0000u);
            aHu[j] = hp;
            aLu[j] = pk_bf16(vv[2*j] - h0, vv[2*j+1] - h1);
        }
#pragma unroll
        for (int m = 0; m < MT; ++m) {
            acc[m] = __builtin_amdgcn_mfma_f32_32x32x16_bf16(ah.s, bh[m].s, acc[m], 0, 0, 0);
            acc[m] = __builtin_amdgcn_mfma_f32_32x32x16_bf16(al.s, bh[m].s, acc[m], 0, 0, 0);
            acc[m] = __builtin_amdgcn_mfma_f32_32x32x16_bf16(ah.s, bl[m].s, acc[m], 0, 0, 0);
        }
        if (c + 1 < KC) {
            __syncthreads();               // bar1: all xst(c) reads done
#pragma unroll
            for (int i = 0; i < 4; ++i) {
                int e = i * 256 + tid, row = e >> 4, kk = e & 15;
                xst[row * XSTR + kk] = px[i];
            }
            store_w<NT, TPT>(wb + ((c + 1) & 1) * HB, tid, pv);
            __syncthreads();               // bar2: xst(c+1) + wb(c+1) visible
        }
    }
    __syncthreads();   // all wb reads done before D-phase overwrites actP alias
    d_phase<MT, NT, 175, 1, true, false>(acc, oP, nullptr, row0, rg, ns, lx, lh, tid);
}

__global__ __launch_bounds__(256, 3)
void mlp_fused(const float* __restrict__ x,
               const float* __restrict__ W1, const float* __restrict__ b1,
               const float* __restrict__ W2, const float* __restrict__ b2,
               const float* __restrict__ W3, const float* __restrict__ b3,
               const float* __restrict__ W4, const float* __restrict__ b4,
               const float* __restrict__ W5, const float* __restrict__ b5,
               float* __restrict__ out)
{
    // uAbuf: L1 weight double-buffer (2 x 6 x 2048 = 24576 B) UNION
    //        actP plane (64 x 184 ushorts = 23552 B) — disjoint lifetimes.
    __shared__ __align__(16) char  uAbuf[24576];
    __shared__ __align__(16) char  wb2[20480];        // L2-5 dbuf (2 x <=5 x 2048)
    __shared__ __align__(16) float xst[64 * XSTR];    // 5120 B   => 50176 B total

    ushort* actP = (ushort*)uAbuf;

    const int tid = threadIdx.x;
    const int l = tid & 63, w = tid >> 6;
    const int rg = w >> 1, ns = w & 1;
    const int lx = l & 31, lh = l >> 5;
    const int row0 = blockIdx.x * 64;

    run_first(x, W1, b1, actP, uAbuf, xst, row0, l, rg, ns, lx, lh, tid);
    run_layer<11, 5, 175, 150, 10, true,  false>(W2, b2, actP, actP, nullptr, wb2, row0, l, rg, ns, lx, lh, tid);
    run_layer<10, 4, 150, 128,  0, true,  false>(W3, b3, actP, actP, nullptr, wb2, row0, l, rg, ns, lx, lh, tid);
    run_layer< 8, 3, 128,  80,  0, true,  false>(W4, b4, actP, actP, nullptr, wb2, row0, l, rg, ns, lx, lh, tid);
    run_layer< 5, 2,  80,  48,  0, false, true >(W5, b5, actP, actP, out,     wb2, row0, l, rg, ns, lx, lh, tid);
}

extern "C" void kernel_launch(void* const* d_in, const int* in_sizes, int n_in,
                              void* d_out, int out_size, void* d_ws, size_t ws_size,
                              hipStream_t stream) {
    (void)in_sizes; (void)n_in; (void)d_ws; (void)ws_size; (void)out_size;
    const float* x  = (const float*)d_in[0];
    const float* W1 = (const float*)d_in[1];
    const float* b1 = (const float*)d_in[2];
    const float* W2 = (const float*)d_in[3];
    const float* b2 = (const float*)d_in[4];
    const float* W3 = (const float*)d_in[5];
    const float* b3 = (const float*)d_in[6];
    const float* W4 = (const float*)d_in[7];
    const float* b4 = (const float*)d_in[8];
    const float* W5 = (const float*)d_in[9];
    const float* b5 = (const float*)d_in[10];
    float* out = (float*)d_out;

    hipLaunchKernelGGL(mlp_fused, dim3(GRID), dim3(256), 0, stream,
                       x, W1, b1, W2, b2, W3, b3, W4, b4, W5, b5, out);
}